// Round 21
// baseline (144.030 us; speedup 1.0000x reference)
//
#include <hip/hip_runtime.h>
#include <hip/hip_bf16.h>

#define NB    8192
#define NF    50
#define NE    64

typedef __attribute__((ext_vector_type(8))) short short8;   // 8 x bf16 MFMA A/B frag (4 VGPR)
typedef __attribute__((ext_vector_type(4))) short short4v;  // 4 x bf16 packed store
typedef __attribute__((ext_vector_type(4))) float float4v;  // MFMA C/D frag

static constexpr float SM_C   = 0.25509667991878083f; // (1/sqrt(32)) * log2(e), folded into Wk
static constexpr float LN_EPS = 1e-6f;

#define MFMA(a, b, c) __builtin_amdgcn_mfma_f32_16x16x32_bf16((a), (b), (c), 0, 0, 0)
#define PRIO_HI() __builtin_amdgcn_s_setprio(1)
#define PRIO_LO() __builtin_amdgcn_s_setprio(0)

__device__ __forceinline__ unsigned short f2bf(float f) {
    return __bfloat16_as_ushort(__float2bfloat16(f));  // native RNE cvt
}

// XOR-swizzled offset into an unpadded [64][64] bf16 tile (8 KB); granule 16 B.
__device__ __forceinline__ int soff(int row, int col) {
    return row * 64 + ((((col >> 3) ^ row) & 7) << 3) + (col & 7);
}

__device__ __forceinline__ void st_pack4(unsigned short* p, float4v v) {
    union { unsigned short u[4]; short4v s; } r;
    r.u[0] = f2bf(v.x); r.u[1] = f2bf(v.y); r.u[2] = f2bf(v.z); r.u[3] = f2bf(v.w);
    *(short4v*)p = r.s;   // ds_write_b64
}

__device__ __forceinline__ float fexp2(float x) {
#if __has_builtin(__builtin_amdgcn_exp2f)
    return __builtin_amdgcn_exp2f(x);
#else
    float r; asm("v_exp_f32 %0, %1" : "=v"(r) : "v"(x)); return r;
#endif
}

__device__ __forceinline__ float frcp(float x) {
#if __has_builtin(__builtin_amdgcn_rcpf)
    return __builtin_amdgcn_rcpf(x);
#else
    return 1.f / x;
#endif
}

// ---- prep: transpose all weights to bf16 [mat][o][e] = W[e][o] in d_ws ----
// slots 0..7 = Wq domains (pi-permuted), 8 = Wk (pi-permuted AND pre-scaled),
// 9 = Wv, 10 = Wr.
__global__ void prep_weights(const float* __restrict__ wq, const float* __restrict__ wk,
                             const float* __restrict__ wv, const float* __restrict__ wr,
                             unsigned short* __restrict__ ws) {
    int i = blockIdx.x * 256 + threadIdx.x;
    if (i >= 11 * 4096) return;
    int m = i >> 12, t = i & 4095, o = t >> 6, e = t & 63;
    int po = (o & 32) | ((o & 12) << 1) | (((o >> 4) & 1) << 2) | (o & 3);
    float v;
    if (m < 8)       v = wq[(m * 64 + e) * 64 + po];
    else if (m == 8) v = wk[e * 64 + po] * SM_C;   // pi + softmax scale (log2e folded)
    else if (m == 9) v = wv[e * 64 + o];
    else             v = wr[e * 64 + o];
    ws[i] = f2bf(v);
}

// ONE 64-lane wave per block, one batch row per wave. No inter-wave cooperation:
// x frags direct from global (one burst), K/Q in registers (pi-permuted weights),
// V^T via the only LDS tile. Wr/gamma/beta hoisted once; s_setprio(1) wraps MFMA
// clusters (proven for independent 1-wave blocks at staggered phases).
__global__ __launch_bounds__(64, 4)
void mdr_mfma(const float* __restrict__ x_g, const int* __restrict__ dom_g,
              const unsigned short* __restrict__ ws,
              const float* __restrict__ gam_g, const float* __restrict__ bet_g,
              float* __restrict__ out_g) {
    __shared__ __align__(16) unsigned short L[NE * NE];   // 8192 B (V^T only)

    const int tid = threadIdx.x;     // 0..63
    const int lm  = tid & 15;
    const int lg  = (tid >> 4) & 3;
    const int b   = blockIdx.x;

    const int dom = dom_g[b] - 1;
    const float* xb = x_g + (size_t)b * (NF * NE);

    // ---------------- x fragments DIRECT from global (one burst; pads zeroed) ---
    short8 xf[4][2];
    {
        float4v a[4][2][2];
        #pragma unroll
        for (int mt = 0; mt < 4; ++mt) {
            const int row = lm + 16 * mt;
            const bool ok = row < NF;
            const float* base = xb + (ok ? row * 64 : 0) + 8 * lg;
            #pragma unroll
            for (int ks = 0; ks < 2; ++ks) {
                float4v z = {0.f, 0.f, 0.f, 0.f};
                a[mt][ks][0] = ok ? *(const float4v*)(base + 32 * ks)     : z;
                a[mt][ks][1] = ok ? *(const float4v*)(base + 32 * ks + 4) : z;
            }
        }
        #pragma unroll
        for (int mt = 0; mt < 4; ++mt)
            #pragma unroll
            for (int ks = 0; ks < 2; ++ks) {
                union { unsigned short u[8]; short8 s; } r;
                #pragma unroll
                for (int k = 0; k < 4; ++k) {
                    r.u[k]     = f2bf(a[mt][ks][0][k]);
                    r.u[4 + k] = f2bf(a[mt][ks][1][k]);
                }
                xf[mt][ks] = r.s;
            }
    }

    // ---------------- V phase: V = x Wv, write V^T [e][tau^-1(f)] to LDS -------
    {
        const unsigned short* wv = ws + 9 * 4096;
        short8 vw[4][2];
        #pragma unroll
        for (int i = 0; i < 4; ++i) {
            vw[i][0] = *(const short8*)(wv + (lm + 16 * i) * 64 + 8 * lg);
            vw[i][1] = *(const short8*)(wv + (lm + 16 * i) * 64 + 8 * lg + 32);
        }
        PRIO_HI();
        #pragma unroll
        for (int mt = 0; mt < 4; ++mt)
            #pragma unroll
            for (int i = 0; i < 4; ++i) {
                float4v acc = {0.f, 0.f, 0.f, 0.f};
                acc = MFMA(xf[mt][0], vw[i][0], acc);
                acc = MFMA(xf[mt][1], vw[i][1], acc);
                st_pack4(L + soff(lm + 16 * i,
                                  32 * (mt >> 1) + 8 * lg + 4 * (mt & 1)), acc);
            }
        PRIO_LO();
    }

    // ---------------- K in registers: kfrag[jt][h] (pi-permuted Wk) ------------
    short8 kfrag[4][2];
    {
        const unsigned short* wk = ws + 8 * 4096;
        short8 kwf[4][2];
        #pragma unroll
        for (int mt = 0; mt < 4; ++mt) {
            kwf[mt][0] = *(const short8*)(wk + (lm + 16 * mt) * 64 + 8 * lg);
            kwf[mt][1] = *(const short8*)(wk + (lm + 16 * mt) * 64 + 8 * lg + 32);
        }
        PRIO_HI();
        #pragma unroll
        for (int jt = 0; jt < 4; ++jt)
            #pragma unroll
            for (int h = 0; h < 2; ++h) {
                float4v z0 = {0.f, 0.f, 0.f, 0.f}, z1 = {0.f, 0.f, 0.f, 0.f};
                z0 = MFMA(kwf[2 * h][0],     xf[jt][0], z0);
                float4v a0 = MFMA(kwf[2 * h][1],     xf[jt][1], z0);
                z1 = MFMA(kwf[2 * h + 1][0], xf[jt][0], z1);
                float4v a1 = MFMA(kwf[2 * h + 1][1], xf[jt][1], z1);
                union { unsigned short uu[8]; short8 s; } r;
                #pragma unroll
                for (int r4 = 0; r4 < 4; ++r4) {
                    r.uu[r4]     = f2bf(a0[r4]);
                    r.uu[4 + r4] = f2bf(a1[r4]);
                }
                kfrag[jt][h] = r.s;
            }
        PRIO_LO();
    }

    // ---------------- Q in registers: qfrag[i][h] (pi-permuted Wq) -------------
    short8 qfrag[4][2];
    {
        const unsigned short* wq = ws + dom * 4096;
        short8 qw[4][2];
        #pragma unroll
        for (int mt = 0; mt < 4; ++mt) {
            qw[mt][0] = *(const short8*)(wq + (lm + 16 * mt) * 64 + 8 * lg);
            qw[mt][1] = *(const short8*)(wq + (lm + 16 * mt) * 64 + 8 * lg + 32);
        }
        PRIO_HI();
        #pragma unroll
        for (int i = 0; i < 4; ++i)
            #pragma unroll
            for (int h = 0; h < 2; ++h) {
                float4v z0 = {0.f, 0.f, 0.f, 0.f}, z1 = {0.f, 0.f, 0.f, 0.f};
                z0 = MFMA(qw[2 * h][0],     xf[i][0], z0);
                float4v a0 = MFMA(qw[2 * h][1],     xf[i][1], z0);
                z1 = MFMA(qw[2 * h + 1][0], xf[i][0], z1);
                float4v a1 = MFMA(qw[2 * h + 1][1], xf[i][1], z1);
                union { unsigned short uu[8]; short8 s; } r;
                #pragma unroll
                for (int r4 = 0; r4 < 4; ++r4) {
                    r.uu[r4]     = f2bf(a0[r4]);
                    r.uu[4 + r4] = f2bf(a1[r4]);
                }
                qfrag[i][h] = r.s;
            }
        PRIO_LO();
    }
    __syncthreads();   // 1-wave block: cheap LDS drain (V^T write->read ordering)

    // ---------------- hoisted once: Wr + gamma/beta (hides under back-half) ----
    short8 rw[4][2];
    float gm[4], bt[4];
    {
        const unsigned short* wr = ws + 10 * 4096;
        #pragma unroll
        for (int c = 0; c < 4; ++c) {
            rw[c][0] = *(const short8*)(wr + (lm + 16 * c) * 64 + 8 * lg);
            rw[c][1] = *(const short8*)(wr + (lm + 16 * c) * 64 + 8 * lg + 32);
            gm[c] = gam_g[dom * 64 + 16 * c + lm];
            bt[c] = bet_g[dom * 64 + 16 * c + lm];
        }
    }

    // ---------------- four INDEPENDENT per-tile back-halves ----------------
    #pragma unroll
    for (int i = 0; i < 4; ++i) {
        short8 pa[2][2];   // [head][k-slice]
        #pragma unroll
        for (int h = 0; h < 2; ++h) {
            float p[4][4];
            float sum = 0.f;
            PRIO_HI();
            #pragma unroll
            for (int jt = 0; jt < 4; ++jt) {
                float4v z = {0.f, 0.f, 0.f, 0.f};
                float4v s = MFMA(kfrag[jt][h], qfrag[i][h], z);
                #pragma unroll
                for (int r = 0; r < 4; ++r) {
                    float e = fexp2(s[r]);
                    p[jt][r] = e; sum += e;
                }
            }
            PRIO_LO();
            sum += __shfl_xor(sum, 16);
            sum += __shfl_xor(sum, 32);
            sum -= 14.f;                 // 14 pad rows contribute 2^0 each
            const float ri = frcp(sum);
            #pragma unroll
            for (int ks = 0; ks < 2; ++ks) {
                union { unsigned short uu[8]; short8 s; } r;
                #pragma unroll
                for (int r4 = 0; r4 < 4; ++r4) {
                    r.uu[r4]     = f2bf(p[2 * ks][r4] * ri);
                    r.uu[4 + r4] = f2bf(p[2 * ks + 1][r4] * ri);
                }
                pa[h][ks] = r.s;
            }
        }
        // PV (V^T from LDS) + R, all MFMA: high prio
        float4v oacc[4];
        #pragma unroll
        for (int c = 0; c < 4; ++c) {
            oacc[c].x = 0.f; oacc[c].y = 0.f; oacc[c].z = 0.f; oacc[c].w = 0.f;
        }
        PRIO_HI();
        #pragma unroll
        for (int h = 0; h < 2; ++h)
            #pragma unroll
            for (int nt2 = 0; nt2 < 2; ++nt2) {
                const int c = 2 * h + nt2;
                short8 vf0 = *(const short8*)(L + soff(16 * c + lm, 8 * lg));
                short8 vf1 = *(const short8*)(L + soff(16 * c + lm, 8 * lg + 32));
                oacc[c] = MFMA(pa[h][0], vf0, oacc[c]);
                oacc[c] = MFMA(pa[h][1], vf1, oacc[c]);
            }
        #pragma unroll
        for (int c = 0; c < 4; ++c) {
            oacc[c] = MFMA(xf[i][0], rw[c][0], oacc[c]);
            oacc[c] = MFMA(xf[i][1], rw[c][1], oacc[c]);
        }
        PRIO_LO();
        // relu + LN + store
        float v[4][4], s1[4], s2[4];
        #pragma unroll
        for (int r = 0; r < 4; ++r) {
            #pragma unroll
            for (int c = 0; c < 4; ++c) v[r][c] = fmaxf(oacc[c][r], 0.f);
            s1[r] = v[r][0] + v[r][1] + v[r][2] + v[r][3];
            s2[r] = v[r][0]*v[r][0] + v[r][1]*v[r][1] + v[r][2]*v[r][2] + v[r][3]*v[r][3];
        }
        #pragma unroll
        for (int msk = 1; msk < 16; msk <<= 1) {
            #pragma unroll
            for (int r = 0; r < 4; ++r) {
                s1[r] += __shfl_xor(s1[r], msk);
                s2[r] += __shfl_xor(s2[r], msk);
            }
        }
        #pragma unroll
        for (int r = 0; r < 4; ++r) {
            const float mean = s1[r] * (1.f / 64.f);
            const float var  = s2[r] * (1.f / 64.f) - mean * mean;
            const float rs   = rsqrtf(var + LN_EPS);
            const int f = 16 * i + 4 * lg + r;
            if (f < NF) {
                float* op = out_g + (size_t)b * (NF * NE) + f * 64 + lm;
                #pragma unroll
                for (int c = 0; c < 4; ++c)
                    op[16 * c] = (v[r][c] - mean) * rs * gm[c] + bt[c];
            }
        }
    }
}

extern "C" void kernel_launch(void* const* d_in, const int* in_sizes, int n_in,
                              void* d_out, int out_size, void* d_ws, size_t ws_size,
                              hipStream_t stream) {
    const float* x   = (const float*)d_in[0];
    const int*   dom = (const int*)  d_in[1];
    const float* wq  = (const float*)d_in[2];
    const float* wk  = (const float*)d_in[3];
    const float* wv  = (const float*)d_in[4];
    const float* wr  = (const float*)d_in[5];
    const float* gam = (const float*)d_in[6];
    const float* bet = (const float*)d_in[7];
    unsigned short* ws = (unsigned short*)d_ws;
    float* out = (float*)d_out;

    hipLaunchKernelGGL(prep_weights, dim3(176), dim3(256), 0, stream, wq, wk, wv, wr, ws);
    hipLaunchKernelGGL(mdr_mfma, dim3(NB), dim3(64), 0, stream,
                       x, dom, ws, gam, bet, out);
}

// Round 22
// 84.676 us; speedup vs baseline: 1.7010x; 1.7010x over previous
//
#include <hip/hip_runtime.h>
#include <hip/hip_bf16.h>

#define NB    8192
#define NF    50
#define NE    64

typedef __attribute__((ext_vector_type(8))) short short8;   // 8 x bf16 MFMA A/B frag (4 VGPR)
typedef __attribute__((ext_vector_type(4))) short short4v;  // 4 x bf16 packed store
typedef __attribute__((ext_vector_type(4))) float float4v;  // MFMA C/D frag

static constexpr float SM_C   = 0.25509667991878083f; // (1/sqrt(32)) * log2(e), folded into Wk
static constexpr float LN_EPS = 1e-6f;

#define MFMA(a, b, c) __builtin_amdgcn_mfma_f32_16x16x32_bf16((a), (b), (c), 0, 0, 0)
#define PRIO_HI() __builtin_amdgcn_s_setprio(1)
#define PRIO_LO() __builtin_amdgcn_s_setprio(0)

__device__ __forceinline__ unsigned short f2bf(float f) {
    return __bfloat16_as_ushort(__float2bfloat16(f));  // native RNE cvt
}

// XOR-swizzled offset into an unpadded [64][64] bf16 tile (8 KB); granule 16 B.
__device__ __forceinline__ int soff(int row, int col) {
    return row * 64 + ((((col >> 3) ^ row) & 7) << 3) + (col & 7);
}

__device__ __forceinline__ void st_pack4(unsigned short* p, float4v v) {
    union { unsigned short u[4]; short4v s; } r;
    r.u[0] = f2bf(v.x); r.u[1] = f2bf(v.y); r.u[2] = f2bf(v.z); r.u[3] = f2bf(v.w);
    *(short4v*)p = r.s;   // ds_write_b64
}

__device__ __forceinline__ float fexp2(float x) {
#if __has_builtin(__builtin_amdgcn_exp2f)
    return __builtin_amdgcn_exp2f(x);
#else
    float r; asm("v_exp_f32 %0, %1" : "=v"(r) : "v"(x)); return r;
#endif
}

__device__ __forceinline__ float frcp(float x) {
#if __has_builtin(__builtin_amdgcn_rcpf)
    return __builtin_amdgcn_rcpf(x);
#else
    return 1.f / x;
#endif
}

// ---- prep: transpose all weights to bf16 [mat][o][e] = W[e][o] in d_ws ----
// slots 0..7 = Wq domains (pi-permuted), 8 = Wk (pi-permuted AND pre-scaled),
// 9 = Wv, 10 = Wr.
__global__ void prep_weights(const float* __restrict__ wq, const float* __restrict__ wk,
                             const float* __restrict__ wv, const float* __restrict__ wr,
                             unsigned short* __restrict__ ws) {
    int i = blockIdx.x * 256 + threadIdx.x;
    if (i >= 11 * 4096) return;
    int m = i >> 12, t = i & 4095, o = t >> 6, e = t & 63;
    int po = (o & 32) | ((o & 12) << 1) | (((o >> 4) & 1) << 2) | (o & 3);
    float v;
    if (m < 8)       v = wq[(m * 64 + e) * 64 + po];
    else if (m == 8) v = wk[e * 64 + po] * SM_C;   // pi + softmax scale (log2e folded)
    else if (m == 9) v = wv[e * 64 + o];
    else             v = wr[e * 64 + o];
    ws[i] = f2bf(v);
}

// ONE 64-lane wave per block, one batch row per wave (R20 structure, VGPR-clean).
// x frags direct from global (one burst), K/Q in registers (pi-permuted weights),
// V^T via the only LDS tile. s_setprio(1) wraps MFMA clusters — the only change
// vs R20 (zero register cost; proven +4-7% for independent 1-wave blocks, m191).
__global__ __launch_bounds__(64, 3)
void mdr_mfma(const float* __restrict__ x_g, const int* __restrict__ dom_g,
              const unsigned short* __restrict__ ws,
              const float* __restrict__ gam_g, const float* __restrict__ bet_g,
              float* __restrict__ out_g) {
    __shared__ __align__(16) unsigned short L[NE * NE];   // 8192 B (V^T only)

    const int tid = threadIdx.x;     // 0..63
    const int lm  = tid & 15;
    const int lg  = (tid >> 4) & 3;
    const int b   = blockIdx.x;

    const int dom = dom_g[b] - 1;
    const float* xb = x_g + (size_t)b * (NF * NE);

    // ---------------- x fragments DIRECT from global (one burst; pads zeroed) ---
    short8 xf[4][2];
    {
        float4v a[4][2][2];
        #pragma unroll
        for (int mt = 0; mt < 4; ++mt) {
            const int row = lm + 16 * mt;
            const bool ok = row < NF;
            const float* base = xb + (ok ? row * 64 : 0) + 8 * lg;
            #pragma unroll
            for (int ks = 0; ks < 2; ++ks) {
                float4v z = {0.f, 0.f, 0.f, 0.f};
                a[mt][ks][0] = ok ? *(const float4v*)(base + 32 * ks)     : z;
                a[mt][ks][1] = ok ? *(const float4v*)(base + 32 * ks + 4) : z;
            }
        }
        #pragma unroll
        for (int mt = 0; mt < 4; ++mt)
            #pragma unroll
            for (int ks = 0; ks < 2; ++ks) {
                union { unsigned short u[8]; short8 s; } r;
                #pragma unroll
                for (int k = 0; k < 4; ++k) {
                    r.u[k]     = f2bf(a[mt][ks][0][k]);
                    r.u[4 + k] = f2bf(a[mt][ks][1][k]);
                }
                xf[mt][ks] = r.s;
            }
    }

    // ---------------- V phase: V = x Wv, write V^T [e][tau^-1(f)] to LDS -------
    {
        const unsigned short* wv = ws + 9 * 4096;
        short8 vw[4][2];
        #pragma unroll
        for (int i = 0; i < 2; ++i) {   // split loads to cap transient regs
            vw[2*i][0]   = *(const short8*)(wv + (lm + 16 * (2*i)) * 64 + 8 * lg);
            vw[2*i][1]   = *(const short8*)(wv + (lm + 16 * (2*i)) * 64 + 8 * lg + 32);
            vw[2*i+1][0] = *(const short8*)(wv + (lm + 16 * (2*i+1)) * 64 + 8 * lg);
            vw[2*i+1][1] = *(const short8*)(wv + (lm + 16 * (2*i+1)) * 64 + 8 * lg + 32);
        }
        PRIO_HI();
        #pragma unroll
        for (int mt = 0; mt < 4; ++mt)
            #pragma unroll
            for (int i = 0; i < 4; ++i) {
                float4v acc = {0.f, 0.f, 0.f, 0.f};
                acc = MFMA(xf[mt][0], vw[i][0], acc);
                acc = MFMA(xf[mt][1], vw[i][1], acc);
                st_pack4(L + soff(lm + 16 * i,
                                  32 * (mt >> 1) + 8 * lg + 4 * (mt & 1)), acc);
            }
        PRIO_LO();
    }

    // ---------------- K in registers: kfrag[jt][h] (pi-permuted Wk) ------------
    short8 kfrag[4][2];
    {
        const unsigned short* wk = ws + 8 * 4096;
        short8 kwf[4][2];
        #pragma unroll
        for (int mt = 0; mt < 4; ++mt) {
            kwf[mt][0] = *(const short8*)(wk + (lm + 16 * mt) * 64 + 8 * lg);
            kwf[mt][1] = *(const short8*)(wk + (lm + 16 * mt) * 64 + 8 * lg + 32);
        }
        PRIO_HI();
        #pragma unroll
        for (int jt = 0; jt < 4; ++jt)
            #pragma unroll
            for (int h = 0; h < 2; ++h) {
                float4v z0 = {0.f, 0.f, 0.f, 0.f}, z1 = {0.f, 0.f, 0.f, 0.f};
                z0 = MFMA(kwf[2 * h][0],     xf[jt][0], z0);
                float4v a0 = MFMA(kwf[2 * h][1],     xf[jt][1], z0);
                z1 = MFMA(kwf[2 * h + 1][0], xf[jt][0], z1);
                float4v a1 = MFMA(kwf[2 * h + 1][1], xf[jt][1], z1);
                union { unsigned short uu[8]; short8 s; } r;
                #pragma unroll
                for (int r4 = 0; r4 < 4; ++r4) {
                    r.uu[r4]     = f2bf(a0[r4]);
                    r.uu[4 + r4] = f2bf(a1[r4]);
                }
                kfrag[jt][h] = r.s;
            }
        PRIO_LO();
    }

    // ---------------- Q in registers: qfrag[i][h] (pi-permuted Wq) -------------
    short8 qfrag[4][2];
    {
        const unsigned short* wq = ws + dom * 4096;
        short8 qw[4][2];
        #pragma unroll
        for (int mt = 0; mt < 4; ++mt) {
            qw[mt][0] = *(const short8*)(wq + (lm + 16 * mt) * 64 + 8 * lg);
            qw[mt][1] = *(const short8*)(wq + (lm + 16 * mt) * 64 + 8 * lg + 32);
        }
        PRIO_HI();
        #pragma unroll
        for (int i = 0; i < 4; ++i)
            #pragma unroll
            for (int h = 0; h < 2; ++h) {
                float4v z0 = {0.f, 0.f, 0.f, 0.f}, z1 = {0.f, 0.f, 0.f, 0.f};
                z0 = MFMA(qw[2 * h][0],     xf[i][0], z0);
                float4v a0 = MFMA(qw[2 * h][1],     xf[i][1], z0);
                z1 = MFMA(qw[2 * h + 1][0], xf[i][0], z1);
                float4v a1 = MFMA(qw[2 * h + 1][1], xf[i][1], z1);
                union { unsigned short uu[8]; short8 s; } r;
                #pragma unroll
                for (int r4 = 0; r4 < 4; ++r4) {
                    r.uu[r4]     = f2bf(a0[r4]);
                    r.uu[4 + r4] = f2bf(a1[r4]);
                }
                qfrag[i][h] = r.s;
            }
        PRIO_LO();
    }
    __syncthreads();   // 1-wave block: cheap LDS drain (V^T write->read ordering)

    float gm[4], bt[4];
    #pragma unroll
    for (int c = 0; c < 4; ++c) {
        gm[c] = gam_g[dom * 64 + 16 * c + lm];
        bt[c] = bet_g[dom * 64 + 16 * c + lm];
    }

    // ---------------- four INDEPENDENT per-tile back-halves ----------------
    #pragma unroll
    for (int i = 0; i < 4; ++i) {
        short8 pa[2][2];   // [head][k-slice]
        #pragma unroll
        for (int h = 0; h < 2; ++h) {
            float p[4][4];
            float sum = 0.f;
            PRIO_HI();
            #pragma unroll
            for (int jt = 0; jt < 4; ++jt) {
                float4v z = {0.f, 0.f, 0.f, 0.f};
                float4v s = MFMA(kfrag[jt][h], qfrag[i][h], z);
                #pragma unroll
                for (int r = 0; r < 4; ++r) {
                    float e = fexp2(s[r]);
                    p[jt][r] = e; sum += e;
                }
            }
            PRIO_LO();
            sum += __shfl_xor(sum, 16);
            sum += __shfl_xor(sum, 32);
            sum -= 14.f;                 // 14 pad rows contribute 2^0 each
            const float ri = frcp(sum);
            #pragma unroll
            for (int ks = 0; ks < 2; ++ks) {
                union { unsigned short uu[8]; short8 s; } r;
                #pragma unroll
                for (int r4 = 0; r4 < 4; ++r4) {
                    r.uu[r4]     = f2bf(p[2 * ks][r4] * ri);
                    r.uu[4 + r4] = f2bf(p[2 * ks + 1][r4] * ri);
                }
                pa[h][ks] = r.s;
            }
        }
        // PV (V^T from LDS)
        float4v oacc[4];
        #pragma unroll
        for (int c = 0; c < 4; ++c) {
            oacc[c].x = 0.f; oacc[c].y = 0.f; oacc[c].z = 0.f; oacc[c].w = 0.f;
        }
        PRIO_HI();
        #pragma unroll
        for (int h = 0; h < 2; ++h)
            #pragma unroll
            for (int nt2 = 0; nt2 < 2; ++nt2) {
                const int c = 2 * h + nt2;
                short8 vf0 = *(const short8*)(L + soff(16 * c + lm, 8 * lg));
                short8 vf1 = *(const short8*)(L + soff(16 * c + lm, 8 * lg + 32));
                oacc[c] = MFMA(pa[h][0], vf0, oacc[c]);
                oacc[c] = MFMA(pa[h][1], vf1, oacc[c]);
            }
        PRIO_LO();
        // R = x Wr accumulated into oacc (per-tile loads; tiles interleave freely)
        {
            const unsigned short* wr = ws + 10 * 4096;
            PRIO_HI();
            #pragma unroll
            for (int c = 0; c < 4; ++c) {
                short8 rw0 = *(const short8*)(wr + (lm + 16 * c) * 64 + 8 * lg);
                short8 rw1 = *(const short8*)(wr + (lm + 16 * c) * 64 + 8 * lg + 32);
                oacc[c] = MFMA(xf[i][0], rw0, oacc[c]);
                oacc[c] = MFMA(xf[i][1], rw1, oacc[c]);
            }
            PRIO_LO();
        }
        // relu + LN + store
        float v[4][4], s1[4], s2[4];
        #pragma unroll
        for (int r = 0; r < 4; ++r) {
            #pragma unroll
            for (int c = 0; c < 4; ++c) v[r][c] = fmaxf(oacc[c][r], 0.f);
            s1[r] = v[r][0] + v[r][1] + v[r][2] + v[r][3];
            s2[r] = v[r][0]*v[r][0] + v[r][1]*v[r][1] + v[r][2]*v[r][2] + v[r][3]*v[r][3];
        }
        #pragma unroll
        for (int msk = 1; msk < 16; msk <<= 1) {
            #pragma unroll
            for (int r = 0; r < 4; ++r) {
                s1[r] += __shfl_xor(s1[r], msk);
                s2[r] += __shfl_xor(s2[r], msk);
            }
        }
        #pragma unroll
        for (int r = 0; r < 4; ++r) {
            const float mean = s1[r] * (1.f / 64.f);
            const float var  = s2[r] * (1.f / 64.f) - mean * mean;
            const float rs   = rsqrtf(var + LN_EPS);
            const int f = 16 * i + 4 * lg + r;
            if (f < NF) {
                float* op = out_g + (size_t)b * (NF * NE) + f * 64 + lm;
                #pragma unroll
                for (int c = 0; c < 4; ++c)
                    op[16 * c] = (v[r][c] - mean) * rs * gm[c] + bt[c];
            }
        }
    }
}

extern "C" void kernel_launch(void* const* d_in, const int* in_sizes, int n_in,
                              void* d_out, int out_size, void* d_ws, size_t ws_size,
                              hipStream_t stream) {
    const float* x   = (const float*)d_in[0];
    const int*   dom = (const int*)  d_in[1];
    const float* wq  = (const float*)d_in[2];
    const float* wk  = (const float*)d_in[3];
    const float* wv  = (const float*)d_in[4];
    const float* wr  = (const float*)d_in[5];
    const float* gam = (const float*)d_in[6];
    const float* bet = (const float*)d_in[7];
    unsigned short* ws = (unsigned short*)d_ws;
    float* out = (float*)d_out;

    hipLaunchKernelGGL(prep_weights, dim3(176), dim3(256), 0, stream, wq, wk, wv, wr, ws);
    hipLaunchKernelGGL(mdr_mfma, dim3(NB), dim3(64), 0, stream,
                       x, dom, ws, gam, bet, out);
}